// Round 2
// baseline (1084.462 us; speedup 1.0000x reference)
//
#include <hip/hip_runtime.h>
#include <hip/hip_bf16.h>
#include <cstddef>

// ILA_10986526343542: linear attention block (fp32 in/out, bf16 intermediates).
// Pipeline (workspace ~90 MB):
//   1) proj_pass(Wk): ek = exp(scale*(Wk@x+bk)) -> bf16 [8,256,16384]
//   2) ksum_pass    : ksum[b,row] = sum_n ek (from the bf16 values)
//   3) t_pass       : Tpart[b,chunk] = ek @ x^T  (256x256 per b, split-K over n)
//   4) ctx_m        : ctx_h = (T_h @ Wv_h^T)/ksum + bv ; M[b] = concat_h(Wo_h @ ctx_h^T)
//   5) proj_pass(Wq): eq = exp(scale*(Wq@x+bq)) -> bf16 (reuses ek buffer) + invZ[b,h,n]
//   6) out_pass     : out[b] = M[b] @ (eq * invZ) + bo

constexpr int   NPIX     = 16384;
constexpr float QK_SCALE = 0.42044820762685725f;  // 32^-0.25

struct alignas(16) US8 { unsigned short v[8]; };

__device__ __forceinline__ float bf2f(unsigned short v) {
    union { unsigned int u; float f; } c; c.u = ((unsigned int)v) << 16; return c.f;
}
__device__ __forceinline__ unsigned short f2bf(float f) {
    __hip_bfloat16 h = __float2bfloat16(f);
    union { __hip_bfloat16 hh; unsigned short s; } c; c.hh = h; return c.s;
}

// ---- 1/5: projection GEMM + exp + bf16 store (+ per-head column sums for q) ----
__global__ __launch_bounds__(256) void proj_pass(
    const float* __restrict__ x, const float* __restrict__ W,
    const float* __restrict__ bias, __hip_bfloat16* __restrict__ eout,
    float* __restrict__ invZ)
{
    __shared__ float As[8][128];
    __shared__ float Bs[8][128];
    __shared__ float red[16][128];
    const int b  = blockIdx.z;
    const int m0 = blockIdx.y * 128;   // 0 or 128 (rows = channels 0..255)
    const int n0 = blockIdx.x * 128;
    const int t  = threadIdx.x;
    const int tx = t & 15, ty = t >> 4;
    const float* xb = x + (size_t)b * 256 * NPIX;

    const int am = t >> 1, ak = (t & 1) * 4;
    const float* wrow = W + (size_t)(m0 + am) * 256;
    const int bk_ = t >> 5, bn = (t & 31) * 4;
    const float* xsrc = xb + (size_t)bk_ * NPIX + n0 + bn;

    float acc[8][8] = {};
    for (int k0 = 0; k0 < 256; k0 += 8) {
        float4 a4 = *(const float4*)(wrow + k0 + ak);
        float4 b4 = *(const float4*)(xsrc + (size_t)k0 * NPIX);
        As[ak+0][am] = a4.x; As[ak+1][am] = a4.y;
        As[ak+2][am] = a4.z; As[ak+3][am] = a4.w;
        *(float4*)&Bs[bk_][bn] = b4;
        __syncthreads();
        #pragma unroll
        for (int kk = 0; kk < 8; ++kk) {
            float a[8], bb[8];
            #pragma unroll
            for (int i = 0; i < 8; ++i) a[i] = As[kk][ty*8 + i];
            #pragma unroll
            for (int j = 0; j < 8; ++j) bb[j] = Bs[kk][tx*8 + j];
            #pragma unroll
            for (int i = 0; i < 8; ++i)
                #pragma unroll
                for (int j = 0; j < 8; ++j)
                    acc[i][j] = fmaf(a[i], bb[j], acc[i][j]);
        }
        __syncthreads();
    }

    float zp[8] = {};
    #pragma unroll
    for (int i = 0; i < 8; ++i) {
        const int gm = m0 + ty*8 + i;
        const float bb_ = bias[gm];
        US8 pack;
        #pragma unroll
        for (int j = 0; j < 8; ++j) {
            float val = expf(QK_SCALE * (acc[i][j] + bb_));
            unsigned short bs = f2bf(val);
            pack.v[j] = bs;
            zp[j] += bf2f(bs);   // sum over the ROUNDED values -> bias cancels
        }
        *(US8*)(eout + ((size_t)b*256 + gm) * NPIX + n0 + tx*8) = pack;
    }

    if (invZ) {  // q pass: per-head (32-row) column sums -> invZ[b,h,n]
        #pragma unroll
        for (int j = 0; j < 8; ++j) red[ty][tx*8 + j] = zp[j];
        __syncthreads();
        const int col = t & 127;
        const int g0  = (t >> 7) * 2;
        #pragma unroll
        for (int gg = 0; gg < 2; ++gg) {
            const int g = g0 + gg;    // head group within tile (rows g*32..g*32+31)
            float z = red[g*4+0][col] + red[g*4+1][col]
                    + red[g*4+2][col] + red[g*4+3][col];
            const int h = (m0 >> 5) + g;
            invZ[((size_t)b*8 + h) * NPIX + n0 + col] = 1.0f / z;
        }
    }
}

// ---- 2: per-row sums of ek (bf16-consistent) -------------------------------
__global__ __launch_bounds__(256) void ksum_pass(
    const __hip_bfloat16* __restrict__ ek, float* __restrict__ ksum)
{
    const int row = blockIdx.x;              // b*256 + c
    const __hip_bfloat16* p = ek + (size_t)row * NPIX;
    const int t = threadIdx.x;
    __shared__ float red[256];
    float s = 0.f;
    for (int i = t*8; i < NPIX; i += 2048) {
        US8 u = *(const US8*)(p + i);
        #pragma unroll
        for (int j = 0; j < 8; ++j) s += bf2f(u.v[j]);
    }
    red[t] = s; __syncthreads();
    for (int st = 128; st > 0; st >>= 1) {
        if (t < st) red[t] += red[t+st];
        __syncthreads();
    }
    if (t == 0) ksum[row] = red[0];
}

// ---- 3: T = ek @ x^T, split-K over n (64x64 tile, 4x4/thread) --------------
__global__ __launch_bounds__(256) void t_pass(
    const __hip_bfloat16* __restrict__ ek, const float* __restrict__ x,
    float* __restrict__ Tpart)
{
    __shared__ float As[32][65];   // [n][m]  (ek rows)
    __shared__ float Bs[32][65];   // [n][c]  (x rows)
    const int tile  = blockIdx.x;                  // 0..15
    const int tm    = (tile >> 2) * 64, tc = (tile & 3) * 64;
    const int chunk = blockIdx.y, b = blockIdx.z;
    const int n0    = chunk * 2048;
    const int t  = threadIdx.x;
    const int tx = t & 15, ty = t >> 4;
    const int srow = t >> 2, snq = (t & 3) * 8;

    const __hip_bfloat16* esrc = ek + ((size_t)b*256 + tm + srow) * NPIX + n0 + snq;
    const float*          xsrc = x  + ((size_t)b*256 + tc + srow) * NPIX + n0 + snq;

    float acc[4][4] = {};
    for (int k0 = 0; k0 < 2048; k0 += 32) {
        US8 u = *(const US8*)(esrc + k0);
        float4 x0 = *(const float4*)(xsrc + k0);
        float4 x1 = *(const float4*)(xsrc + k0 + 4);
        #pragma unroll
        for (int j = 0; j < 8; ++j) As[snq + j][srow] = bf2f(u.v[j]);
        Bs[snq+0][srow] = x0.x; Bs[snq+1][srow] = x0.y;
        Bs[snq+2][srow] = x0.z; Bs[snq+3][srow] = x0.w;
        Bs[snq+4][srow] = x1.x; Bs[snq+5][srow] = x1.y;
        Bs[snq+6][srow] = x1.z; Bs[snq+7][srow] = x1.w;
        __syncthreads();
        #pragma unroll
        for (int kk = 0; kk < 32; ++kk) {
            float a[4], bb[4];
            #pragma unroll
            for (int i = 0; i < 4; ++i) a[i]  = As[kk][ty*4 + i];
            #pragma unroll
            for (int j = 0; j < 4; ++j) bb[j] = Bs[kk][tx*4 + j];
            #pragma unroll
            for (int i = 0; i < 4; ++i)
                #pragma unroll
                for (int j = 0; j < 4; ++j)
                    acc[i][j] = fmaf(a[i], bb[j], acc[i][j]);
        }
        __syncthreads();
    }
    float* o = Tpart + (((size_t)b*8 + chunk)*256 + tm + ty*4) * 256 + tc + tx*4;
    #pragma unroll
    for (int i = 0; i < 4; ++i)
        #pragma unroll
        for (int j = 0; j < 4; ++j)
            o[(size_t)i*256 + j] = acc[i][j];
}

// ---- 4: reduce T, ctx = T@Wv^T/ksum + bv, M = Wo@ctx^T ---------------------
__global__ __launch_bounds__(256) void ctx_m(
    const float* __restrict__ Tpart, const float* __restrict__ ksum,
    const float* __restrict__ Wv, const float* __restrict__ bv,
    const float* __restrict__ Wo, float* __restrict__ Mb)
{
    __shared__ float Ts[32][257];
    __shared__ float cs[32][64];
    const int h = blockIdx.x, b = blockIdx.y;
    const int t = threadIdx.x;

    for (int idx = t; idx < 8192; idx += 256) {
        const int d = idx >> 8, c = idx & 255;
        float s = 0.f;
        #pragma unroll
        for (int ch = 0; ch < 8; ++ch)
            s += Tpart[(((size_t)b*8 + ch)*256 + h*32 + d)*256 + c];
        Ts[d][c] = s;
    }
    __syncthreads();
    {
        const int d = t >> 3, e0 = (t & 7) * 8;
        const float inv = 1.0f / ksum[b*256 + h*32 + d];
        for (int e = e0; e < e0 + 8; ++e) {
            const float* wv = Wv + (size_t)(h*64 + e) * 256;
            float s = 0.f;
            for (int c = 0; c < 256; ++c) s = fmaf(Ts[d][c], wv[c], s);
            cs[d][e] = s * inv + bv[h*64 + e];
        }
    }
    __syncthreads();
    {
        float wo[64];
        const float* wr = Wo + (size_t)t * 512 + h*64;
        #pragma unroll
        for (int e = 0; e < 64; ++e) wo[e] = wr[e];
        float* mrow = Mb + ((size_t)b*256 + t) * 256 + h*32;
        for (int d = 0; d < 32; ++d) {
            float s = 0.f;
            #pragma unroll
            for (int e = 0; e < 64; ++e) s = fmaf(wo[e], cs[d][e], s);
            mrow[d] = s;
        }
    }
}

// ---- 6: out = M[b] @ (eq * invZ) + bo --------------------------------------
__global__ __launch_bounds__(256) void out_pass(
    const __hip_bfloat16* __restrict__ eq, const float* __restrict__ invZ,
    const float* __restrict__ Mb, const float* __restrict__ bo,
    float* __restrict__ out)
{
    __shared__ float As[8][128];
    __shared__ float Bs[8][128];
    const int b  = blockIdx.z;
    const int m0 = blockIdx.y * 128, n0 = blockIdx.x * 128;
    const int t  = threadIdx.x;
    const int tx = t & 15, ty = t >> 4;
    const int am = t >> 1, ak = (t & 1) * 4;
    const float* arow = Mb + ((size_t)b*256 + m0 + am) * 256;
    const int bk_ = t >> 5, bn = (t & 31) * 4;
    const __hip_bfloat16* esrc = eq + ((size_t)b*256 + bk_) * NPIX + n0 + bn;

    float acc[8][8] = {};
    for (int k0 = 0; k0 < 256; k0 += 8) {
        float4 a4 = *(const float4*)(arow + k0 + ak);
        ushort4 u = *(const ushort4*)(esrc + (size_t)k0 * NPIX);
        const int h = (k0 + bk_) >> 5;
        float4 iz = *(const float4*)(invZ + ((size_t)b*8 + h) * NPIX + n0 + bn);
        As[ak+0][am] = a4.x; As[ak+1][am] = a4.y;
        As[ak+2][am] = a4.z; As[ak+3][am] = a4.w;
        Bs[bk_][bn+0] = bf2f(u.x) * iz.x;
        Bs[bk_][bn+1] = bf2f(u.y) * iz.y;
        Bs[bk_][bn+2] = bf2f(u.z) * iz.z;
        Bs[bk_][bn+3] = bf2f(u.w) * iz.w;
        __syncthreads();
        #pragma unroll
        for (int kk = 0; kk < 8; ++kk) {
            float a[8], bb[8];
            #pragma unroll
            for (int i = 0; i < 8; ++i) a[i] = As[kk][ty*8 + i];
            #pragma unroll
            for (int j = 0; j < 8; ++j) bb[j] = Bs[kk][tx*8 + j];
            #pragma unroll
            for (int i = 0; i < 8; ++i)
                #pragma unroll
                for (int j = 0; j < 8; ++j)
                    acc[i][j] = fmaf(a[i], bb[j], acc[i][j]);
        }
        __syncthreads();
    }

    #pragma unroll
    for (int i = 0; i < 8; ++i) {
        const int gm = m0 + ty*8 + i;
        const float bias = bo[gm];
        float* dst = out + ((size_t)b*256 + gm) * NPIX;
        float4 o0, o1;
        o0.x = acc[i][0]+bias; o0.y = acc[i][1]+bias;
        o0.z = acc[i][2]+bias; o0.w = acc[i][3]+bias;
        o1.x = acc[i][4]+bias; o1.y = acc[i][5]+bias;
        o1.z = acc[i][6]+bias; o1.w = acc[i][7]+bias;
        *(float4*)(dst + n0 + tx*8)     = o0;
        *(float4*)(dst + n0 + tx*8 + 4) = o1;
    }
}

// ---------------------------------------------------------------------------
extern "C" void kernel_launch(void* const* d_in, const int* in_sizes, int n_in,
                              void* d_out, int out_size, void* d_ws, size_t ws_size,
                              hipStream_t stream)
{
    const float* x  = (const float*)d_in[0];
    const float* Wq = (const float*)d_in[1];
    const float* bq = (const float*)d_in[2];
    const float* Wk = (const float*)d_in[3];
    const float* bk = (const float*)d_in[4];
    const float* Wv = (const float*)d_in[5];
    const float* bv = (const float*)d_in[6];
    const float* Wo = (const float*)d_in[7];
    const float* bo = (const float*)d_in[8];
    float* out = (float*)d_out;

    // workspace layout (bytes), total 90,185,728 (~90 MB):
    //   [0,          67108864)  ekq   bf16 [8*256*16384]  (ek, then reused as eq)
    //   [67108864,   83886080)  Tpart f32  [8][8][256][256]
    //   [83886080,   88080384)  invZ  f32  [8][8][16384]
    //   [88080384,   88088576)  ksum  f32  [2048]
    //   [88088576,   90185728)  Mb    f32  [8][256][256]
    if (ws_size < (size_t)90185728) return;  // guard: fail loud (absmax) not crash
    char* w = (char*)d_ws;
    __hip_bfloat16* ekq = (__hip_bfloat16*)w;
    float* Tpart = (float*)(w + 67108864);
    float* invZ  = (float*)(w + 83886080);
    float* ksum  = (float*)(w + 88080384);
    float* Mb    = (float*)(w + 88088576);

    proj_pass<<<dim3(128, 2, 8), 256, 0, stream>>>(x, Wk, bk, ekq, nullptr);
    ksum_pass<<<2048,            256, 0, stream>>>(ekq, ksum);
    t_pass   <<<dim3(16, 8, 8),  256, 0, stream>>>(ekq, x, Tpart);
    ctx_m    <<<dim3(8, 8),      256, 0, stream>>>(Tpart, ksum, Wv, bv, Wo, Mb);
    proj_pass<<<dim3(128, 2, 8), 256, 0, stream>>>(x, Wq, bq, ekq, invZ);
    out_pass <<<dim3(128, 2, 8), 256, 0, stream>>>(ekq, invZ, Mb, bo, out);
}

// Round 3
// 382.577 us; speedup vs baseline: 2.8346x; 2.8346x over previous
//
#include <hip/hip_runtime.h>
#include <hip/hip_bf16.h>
#include <cstddef>

// ILA_10986526343542: linear attention block, bf16-MFMA pipeline.
// x:[8,256,128,128] fp32. Math:
//   ek  = exp(s*(Wk@x+bk)) bf16 [b][c][n]      (proj_mfma<false>)
//   ksum[b,c] = sum_n ek                        (ksum_pass)
//   T   = ek @ x^T  (split over 8 n-chunks)     (t_mfma -> Tpart)
//   ctx = T@Wv^T/ksum + bv ; M = Wo@ctx^T bf16  (ctx_m)
//   eqT = exp(s*(Wq@x+bq)) bf16 [b][n][c]      (proj_mfma<true>)
//   invZ[b,n,h] = 1/sum_{c in head} eqT[n][c]   (invz_pass)
//   out = M @ (eqT^T * invZ) + bo               (out_mfma)

constexpr int   NPIX     = 16384;
constexpr float QK_SCALE = 0.42044820762685725f;  // 32^-0.25

typedef __attribute__((ext_vector_type(8))) short          bf16x8;
typedef __attribute__((ext_vector_type(8))) unsigned short u16x8;
typedef __attribute__((ext_vector_type(4))) float          f32x4;

union BF8 { bf16x8 v; unsigned short u[8]; };

__device__ __forceinline__ float bf2f(unsigned short v) {
    union { unsigned int u; float f; } c; c.u = ((unsigned int)v) << 16; return c.f;
}
__device__ __forceinline__ unsigned short f2bf(float f) {
    union { __hip_bfloat16 h; unsigned short s; } c; c.h = __float2bfloat16(f); return c.s;
}

// ---- 0: weights to bf16 ----------------------------------------------------
__global__ __launch_bounds__(256) void prep(
    const float* __restrict__ Wq, const float* __restrict__ Wk,
    unsigned short* __restrict__ Wqb, unsigned short* __restrict__ Wkb)
{
    const int i = blockIdx.x * 256 + threadIdx.x;   // 65536 total
    Wqb[i] = f2bf(Wq[i]);
    Wkb[i] = f2bf(Wk[i]);
}

// ---- 1/5: projection via MFMA, no-LDS K-loop, LDS-bounce epilogue ----------
// QPASS=false: eout = ek  [b][c][n] row-major
// QPASS=true : eout = eqT [b][n][c] row-major (transposed store)
template<bool QPASS>
__global__ __launch_bounds__(256) void proj_mfma(
    const float* __restrict__ x, const unsigned short* __restrict__ Wb,
    const float* __restrict__ bias, unsigned short* __restrict__ eout)
{
    __shared__ unsigned short Cs[4][64][72];
    const int b  = blockIdx.z;
    const int m0 = blockIdx.y * 128;
    const int n0 = blockIdx.x * 128;
    const int t  = threadIdx.x;
    const int w  = t >> 6, l = t & 63;
    const int mw = m0 + (w & 1) * 64;     // wave's 64 output channels
    const int nw = n0 + (w >> 1) * 64;    // wave's 64 pixels
    const int lm = l & 15, lg = l >> 4;

    const float* xb = x + (size_t)b * 256 * NPIX;

    f32x4 acc[4][4] = {};
    for (int k0 = 0; k0 < 256; k0 += 32) {
        const int kf = k0 + lg * 8;
        bf16x8 afr[4], bfr[4];
        #pragma unroll
        for (int i = 0; i < 4; ++i)
            afr[i] = *(const bf16x8*)(Wb + (size_t)(mw + i*16 + lm) * 256 + kf);
        #pragma unroll
        for (int j = 0; j < 4; ++j) {
            BF8 p;
            const float* col = xb + (size_t)kf * NPIX + (nw + j*16 + lm);
            #pragma unroll
            for (int jj = 0; jj < 8; ++jj)
                p.u[jj] = f2bf(col[(size_t)jj * NPIX]);
            bfr[j] = p.v;
        }
        #pragma unroll
        for (int i = 0; i < 4; ++i)
            #pragma unroll
            for (int j = 0; j < 4; ++j)
                acc[i][j] = __builtin_amdgcn_mfma_f32_16x16x32_bf16(afr[i], bfr[j], acc[i][j], 0, 0, 0);
    }

    // epilogue: exp + bf16, bounce through LDS for coalesced stores
    #pragma unroll
    for (int i = 0; i < 4; ++i) {
        const f32x4 bb4 = *(const f32x4*)(bias + mw + i*16 + lg*4);
        #pragma unroll
        for (int r = 0; r < 4; ++r) {
            const int row = i*16 + lg*4 + r;
            #pragma unroll
            for (int j = 0; j < 4; ++j) {
                const int col = j*16 + lm;
                const unsigned short bs = f2bf(__expf(QK_SCALE * (acc[i][j][r] + bb4[r])));
                if (QPASS) Cs[w][col][row] = bs;   // [n-local][c-local]
                else       Cs[w][row][col] = bs;   // [c-local][n-local]
            }
        }
    }
    __syncthreads();

    unsigned short* dst;
    if (QPASS) dst = eout + ((size_t)b * NPIX + nw + l) * 256 + mw;   // eqT row
    else       dst = eout + ((size_t)b * 256 + mw + l) * NPIX + nw;   // ek row
    #pragma unroll
    for (int s8 = 0; s8 < 8; ++s8)
        *(u16x8*)(dst + s8*8) = *(const u16x8*)&Cs[w][l][s8*8];
}

// ---- 2: per-row sums of ek (bf16-consistent) -------------------------------
__global__ __launch_bounds__(256) void ksum_pass(
    const unsigned short* __restrict__ ek, float* __restrict__ ksum)
{
    const int row = blockIdx.x;              // b*256 + c
    const unsigned short* p = ek + (size_t)row * NPIX;
    const int t = threadIdx.x;
    __shared__ float red[256];
    float s = 0.f;
    for (int i = t*8; i < NPIX; i += 2048) {
        u16x8 u = *(const u16x8*)(p + i);
        #pragma unroll
        for (int j = 0; j < 8; ++j) s += bf2f(u[j]);
    }
    red[t] = s; __syncthreads();
    for (int st = 128; st > 0; st >>= 1) {
        if (t < st) red[t] += red[t+st];
        __syncthreads();
    }
    if (t == 0) ksum[row] = red[0];
}

// ---- 3: Tpart[b][chunk] = ek @ x^T via MFMA (128x128 tile, K=2048) ---------
__global__ __launch_bounds__(256) void t_mfma(
    const unsigned short* __restrict__ ek, const float* __restrict__ x,
    float* __restrict__ Tpart)
{
    __shared__ unsigned short As[128][40];
    __shared__ unsigned short Bs[128][40];
    const int quad  = blockIdx.x;        // 0..3 -> (m-tile, c-tile)
    const int chunk = blockIdx.y;        // 0..7
    const int b     = blockIdx.z;
    const int mt = (quad >> 1) * 128;    // key-channel tile
    const int ct = (quad & 1) * 128;     // channel tile
    const int t  = threadIdx.x;
    const int w  = t >> 6, l = t & 63;
    const int lm = l & 15, lg = l >> 4;
    const int mw = (w & 1) * 64, cw = (w >> 1) * 64;
    const int sr = t >> 1, sh = (t & 1) * 16;

    const unsigned short* ekb = ek + ((size_t)b*256 + mt) * NPIX;
    const float*          xb  = x  + ((size_t)b*256 + ct) * NPIX;

    f32x4 acc[4][4] = {};
    const int p0base = chunk * 2048;
    for (int p0 = p0base; p0 < p0base + 2048; p0 += 32) {
        {   // stage A: ek rows (bf16 direct)
            const unsigned short* src = ekb + (size_t)sr * NPIX + p0 + sh;
            *(u16x8*)&As[sr][sh]     = *(const u16x8*)src;
            *(u16x8*)&As[sr][sh + 8] = *(const u16x8*)(src + 8);
        }
        {   // stage B: x rows (fp32 -> bf16)
            const float* src = xb + (size_t)sr * NPIX + p0 + sh;
            u16x8 a, c;
            #pragma unroll
            for (int u = 0; u < 8; ++u) { a[u] = f2bf(src[u]); c[u] = f2bf(src[8+u]); }
            *(u16x8*)&Bs[sr][sh]     = a;
            *(u16x8*)&Bs[sr][sh + 8] = c;
        }
        __syncthreads();
        bf16x8 afr[4], bfr[4];
        #pragma unroll
        for (int i = 0; i < 4; ++i) afr[i] = *(const bf16x8*)&As[mw + i*16 + lm][lg*8];
        #pragma unroll
        for (int j = 0; j < 4; ++j) bfr[j] = *(const bf16x8*)&Bs[cw + j*16 + lm][lg*8];
        #pragma unroll
        for (int i = 0; i < 4; ++i)
            #pragma unroll
            for (int j = 0; j < 4; ++j)
                acc[i][j] = __builtin_amdgcn_mfma_f32_16x16x32_bf16(afr[i], bfr[j], acc[i][j], 0, 0, 0);
        __syncthreads();
    }

    float* dst = Tpart + (((size_t)b*8 + chunk) * 256) * 256;
    #pragma unroll
    for (int i = 0; i < 4; ++i)
        #pragma unroll
        for (int r = 0; r < 4; ++r) {
            const int gm = mt + mw + i*16 + lg*4 + r;
            #pragma unroll
            for (int j = 0; j < 4; ++j)
                dst[(size_t)gm * 256 + ct + cw + j*16 + lm] = acc[i][j][r];
        }
}

// ---- 4: reduce T, ctx = T@Wv^T/ksum + bv, M = Wo@ctx^T (bf16 out) ----------
__global__ __launch_bounds__(256) void ctx_m(
    const float* __restrict__ Tpart, const float* __restrict__ ksum,
    const float* __restrict__ Wv, const float* __restrict__ bv,
    const float* __restrict__ Wo, unsigned short* __restrict__ Mb)
{
    __shared__ float Ts[32][257];
    __shared__ float cs[32][64];
    const int h = blockIdx.x, b = blockIdx.y;
    const int t = threadIdx.x;

    for (int idx = t; idx < 8192; idx += 256) {
        const int d = idx >> 8, c = idx & 255;
        float s = 0.f;
        #pragma unroll
        for (int ch = 0; ch < 8; ++ch)
            s += Tpart[(((size_t)b*8 + ch)*256 + h*32 + d)*256 + c];
        Ts[d][c] = s;
    }
    __syncthreads();
    {
        const int d = t >> 3, e0 = (t & 7) * 8;
        const float inv = 1.0f / ksum[b*256 + h*32 + d];
        for (int e = e0; e < e0 + 8; ++e) {
            const float* wv = Wv + (size_t)(h*64 + e) * 256;
            float s = 0.f;
            for (int c = 0; c < 256; ++c) s = fmaf(Ts[d][c], wv[c], s);
            cs[d][e] = s * inv + bv[h*64 + e];
        }
    }
    __syncthreads();
    {
        float wo[64];
        const float* wr = Wo + (size_t)t * 512 + h*64;
        #pragma unroll
        for (int e = 0; e < 64; ++e) wo[e] = wr[e];
        unsigned short* mrow = Mb + ((size_t)b*256 + t) * 256 + h*32;
        for (int d = 0; d < 32; ++d) {
            float s = 0.f;
            #pragma unroll
            for (int e = 0; e < 64; ++e) s = fmaf(wo[e], cs[d][e], s);
            mrow[d] = f2bf(s);
        }
    }
}

// ---- 6: invZ[b][n][h] = 1 / sum_{c in head h} eqT[b][n][c] -----------------
__global__ __launch_bounds__(256) void invz_pass(
    const unsigned short* __restrict__ eqT, float* __restrict__ invZ)
{
    const int b = blockIdx.y;
    const int n = blockIdx.x * 256 + threadIdx.x;
    const unsigned short* row = eqT + ((size_t)b * NPIX + n) * 256;
    float* o = invZ + ((size_t)b * NPIX + n) * 8;
    #pragma unroll
    for (int h = 0; h < 8; ++h) {
        float s = 0.f;
        #pragma unroll
        for (int u = 0; u < 4; ++u) {
            u16x8 v = *(const u16x8*)(row + h*32 + u*8);
            #pragma unroll
            for (int e = 0; e < 8; ++e) s += bf2f(v[e]);
        }
        o[h] = 1.0f / s;
    }
}

// ---- 7: out = M[b] @ (eqT^T * invZ) + bo via MFMA --------------------------
__global__ __launch_bounds__(256) void out_mfma(
    const unsigned short* __restrict__ eqT, const float* __restrict__ invZ,
    const unsigned short* __restrict__ Mb, const float* __restrict__ bo,
    float* __restrict__ out)
{
    __shared__ unsigned short As[128][40];
    __shared__ unsigned short Bs[128][40];
    const int b  = blockIdx.z;
    const int m0 = blockIdx.y * 128;
    const int n0 = blockIdx.x * 128;
    const int t  = threadIdx.x;
    const int w  = t >> 6, l = t & 63;
    const int lm = l & 15, lg = l >> 4;
    const int mw = (w & 1) * 64, nw = (w >> 1) * 64;
    const int sr = t >> 1, sh = (t & 1) * 16;

    const unsigned short* Ab  = Mb  + ((size_t)b*256 + m0) * 256;
    const unsigned short* Bb  = eqT + (size_t)b * NPIX * 256;
    const float*          izb = invZ + (size_t)b * NPIX * 8;

    f32x4 acc[4][4] = {};
    for (int k0 = 0; k0 < 256; k0 += 32) {
        {   // stage A: Mb rows
            const unsigned short* src = Ab + (size_t)sr * 256 + k0 + sh;
            *(u16x8*)&As[sr][sh]     = *(const u16x8*)src;
            *(u16x8*)&As[sr][sh + 8] = *(const u16x8*)(src + 8);
        }
        {   // stage B: eqT rows * invZ (head = k0>>5, one head per K-step)
            const unsigned short* src = Bb + (size_t)(n0 + sr) * 256 + k0 + sh;
            const float iz = izb[(size_t)(n0 + sr) * 8 + (k0 >> 5)];
            u16x8 a = *(const u16x8*)src, c = *(const u16x8*)(src + 8);
            u16x8 oa, oc;
            #pragma unroll
            for (int u = 0; u < 8; ++u) {
                oa[u] = f2bf(bf2f(a[u]) * iz);
                oc[u] = f2bf(bf2f(c[u]) * iz);
            }
            *(u16x8*)&Bs[sr][sh]     = oa;
            *(u16x8*)&Bs[sr][sh + 8] = oc;
        }
        __syncthreads();
        bf16x8 afr[4], bfr[4];
        #pragma unroll
        for (int i = 0; i < 4; ++i) afr[i] = *(const bf16x8*)&As[mw + i*16 + lm][lg*8];
        #pragma unroll
        for (int j = 0; j < 4; ++j) bfr[j] = *(const bf16x8*)&Bs[nw + j*16 + lm][lg*8];
        #pragma unroll
        for (int i = 0; i < 4; ++i)
            #pragma unroll
            for (int j = 0; j < 4; ++j)
                acc[i][j] = __builtin_amdgcn_mfma_f32_16x16x32_bf16(afr[i], bfr[j], acc[i][j], 0, 0, 0);
        __syncthreads();
    }

    #pragma unroll
    for (int i = 0; i < 4; ++i) {
        const f32x4 bb4 = *(const f32x4*)(bo + m0 + mw + i*16 + lg*4);
        #pragma unroll
        for (int r = 0; r < 4; ++r) {
            const int gm = m0 + mw + i*16 + lg*4 + r;
            float* dst = out + ((size_t)b*256 + gm) * NPIX + n0 + nw;
            #pragma unroll
            for (int j = 0; j < 4; ++j)
                dst[j*16 + lm] = acc[i][j][r] + bb4[r];
        }
    }
}

// ---------------------------------------------------------------------------
extern "C" void kernel_launch(void* const* d_in, const int* in_sizes, int n_in,
                              void* d_out, int out_size, void* d_ws, size_t ws_size,
                              hipStream_t stream)
{
    const float* x  = (const float*)d_in[0];
    const float* Wq = (const float*)d_in[1];
    const float* bq = (const float*)d_in[2];
    const float* Wk = (const float*)d_in[3];
    const float* bk = (const float*)d_in[4];
    const float* Wv = (const float*)d_in[5];
    const float* bv = (const float*)d_in[6];
    const float* Wo = (const float*)d_in[7];
    const float* bo = (const float*)d_in[8];
    float* out = (float*)d_out;

    // workspace (89,399,296 B total; ek and eqT share the first region —
    // ek is dead after t_mfma, eqT written afterwards):
    //   [0,          67108864)  ek / eqT  bf16
    //   [67108864,   83886080)  Tpart f32 [8][8][256][256]
    //   [83886080,   88080384)  invZ  f32 [8][16384][8]
    //   [88080384,   88088576)  ksum  f32 [2048]
    //   [88088576,   89137152)  Mb    bf16 [8][256][256]
    //   [89137152,   89268224)  Wqb   bf16
    //   [89268224,   89399296)  Wkb   bf16
    if (ws_size < (size_t)89399296) return;  // fail loud, not crash
    char* wsb = (char*)d_ws;
    unsigned short* ekq  = (unsigned short*)wsb;
    float*          Tpart= (float*)(wsb + 67108864);
    float*          invZ = (float*)(wsb + 83886080);
    float*          ksum = (float*)(wsb + 88080384);
    unsigned short* Mb   = (unsigned short*)(wsb + 88088576);
    unsigned short* Wqb  = (unsigned short*)(wsb + 89137152);
    unsigned short* Wkb  = (unsigned short*)(wsb + 89268224);

    prep             <<<256,              256, 0, stream>>>(Wq, Wk, Wqb, Wkb);
    proj_mfma<false> <<<dim3(128, 2, 8),  256, 0, stream>>>(x, Wkb, bk, ekq);
    ksum_pass        <<<2048,             256, 0, stream>>>(ekq, ksum);
    t_mfma           <<<dim3(4, 8, 8),    256, 0, stream>>>(ekq, x, Tpart);
    ctx_m            <<<dim3(8, 8),       256, 0, stream>>>(Tpart, ksum, Wv, bv, Wo, Mb);
    proj_mfma<true>  <<<dim3(128, 2, 8),  256, 0, stream>>>(x, Wqb, bq, ekq);
    invz_pass        <<<dim3(64, 8),      256, 0, stream>>>(ekq, invZ);
    out_mfma         <<<dim3(128, 2, 8),  256, 0, stream>>>(ekq, invZ, Mb, bo, out);
}

// Round 4
// 336.471 us; speedup vs baseline: 3.2231x; 1.1370x over previous
//
#include <hip/hip_runtime.h>
#include <hip/hip_bf16.h>
#include <cstddef>

// ILA_10986526343542: linear attention block, bf16-MFMA pipeline.
// x:[8,256,128,128] fp32. Math:
//   ek  = exp(s*(Wk@x+bk)) bf16 [b][c][n]      (proj_mfma<false>)
//   ksum[b,c] = sum_n ek                        (ksum_pass)
//   T   = ek @ x^T  (split over 8 n-chunks)     (t_mfma -> Tpart)
//   Tred= (sum_chunks T)/ksum  (in-place ch.0)  (treduce)
//   ctx = Tred@Wv^T + bv                        (ctx_pass)
//   M   = Wo_h @ ctx_h^T  (bf16)                (mpass)
//   eqT = exp(s*(Wq@x+bq)) bf16 [b][n][c]      (proj_mfma<true>)
//   invZ[b,n,h] = 1/sum_{c in head} eqT[n][c]   (invz_pass)
//   out = M @ (eqT^T * invZ) + bo               (out_mfma)

constexpr int   NPIX     = 16384;
constexpr float QK_SCALE = 0.42044820762685725f;  // 32^-0.25

typedef __attribute__((ext_vector_type(8))) short          bf16x8;
typedef __attribute__((ext_vector_type(8))) unsigned short u16x8;
typedef __attribute__((ext_vector_type(4))) float          f32x4;

union BF8 { bf16x8 v; unsigned short u[8]; };

__device__ __forceinline__ float bf2f(unsigned short v) {
    union { unsigned int u; float f; } c; c.u = ((unsigned int)v) << 16; return c.f;
}
__device__ __forceinline__ unsigned short f2bf(float f) {
    union { __hip_bfloat16 h; unsigned short s; } c; c.h = __float2bfloat16(f); return c.s;
}

// ---- 0: weights to bf16 ----------------------------------------------------
__global__ __launch_bounds__(256) void prep(
    const float* __restrict__ Wq, const float* __restrict__ Wk,
    unsigned short* __restrict__ Wqb, unsigned short* __restrict__ Wkb)
{
    const int i = blockIdx.x * 256 + threadIdx.x;   // 65536 total
    Wqb[i] = f2bf(Wq[i]);
    Wkb[i] = f2bf(Wk[i]);
}

// ---- 1/7: projection via MFMA, no-LDS K-loop, LDS-bounce epilogue ----------
// QPASS=false: eout = ek  [b][c][n] row-major
// QPASS=true : eout = eqT [b][n][c] row-major (transposed store)
template<bool QPASS>
__global__ __launch_bounds__(256) void proj_mfma(
    const float* __restrict__ x, const unsigned short* __restrict__ Wb,
    const float* __restrict__ bias, unsigned short* __restrict__ eout)
{
    __shared__ unsigned short Cs[4][64][72];
    const int b  = blockIdx.z;
    const int m0 = blockIdx.y * 128;
    const int n0 = blockIdx.x * 128;
    const int t  = threadIdx.x;
    const int w  = t >> 6, l = t & 63;
    const int mw = m0 + (w & 1) * 64;     // wave's 64 output channels
    const int nw = n0 + (w >> 1) * 64;    // wave's 64 pixels
    const int lm = l & 15, lg = l >> 4;

    const float* xb = x + (size_t)b * 256 * NPIX;

    f32x4 acc[4][4] = {};
    for (int k0 = 0; k0 < 256; k0 += 32) {
        const int kf = k0 + lg * 8;
        bf16x8 afr[4], bfr[4];
        #pragma unroll
        for (int i = 0; i < 4; ++i)
            afr[i] = *(const bf16x8*)(Wb + (size_t)(mw + i*16 + lm) * 256 + kf);
        #pragma unroll
        for (int j = 0; j < 4; ++j) {
            BF8 p;
            const float* col = xb + (size_t)kf * NPIX + (nw + j*16 + lm);
            #pragma unroll
            for (int jj = 0; jj < 8; ++jj)
                p.u[jj] = f2bf(col[(size_t)jj * NPIX]);
            bfr[j] = p.v;
        }
        #pragma unroll
        for (int i = 0; i < 4; ++i)
            #pragma unroll
            for (int j = 0; j < 4; ++j)
                acc[i][j] = __builtin_amdgcn_mfma_f32_16x16x32_bf16(afr[i], bfr[j], acc[i][j], 0, 0, 0);
    }

    // epilogue: exp + bf16, bounce through LDS for coalesced stores
    #pragma unroll
    for (int i = 0; i < 4; ++i) {
        const f32x4 bb4 = *(const f32x4*)(bias + mw + i*16 + lg*4);
        #pragma unroll
        for (int r = 0; r < 4; ++r) {
            const int row = i*16 + lg*4 + r;
            #pragma unroll
            for (int j = 0; j < 4; ++j) {
                const int col = j*16 + lm;
                const unsigned short bs = f2bf(__expf(QK_SCALE * (acc[i][j][r] + bb4[r])));
                if (QPASS) Cs[w][col][row] = bs;   // [n-local][c-local]
                else       Cs[w][row][col] = bs;   // [c-local][n-local]
            }
        }
    }
    __syncthreads();

    unsigned short* dst;
    if (QPASS) dst = eout + ((size_t)b * NPIX + nw + l) * 256 + mw;   // eqT row
    else       dst = eout + ((size_t)b * 256 + mw + l) * NPIX + nw;   // ek row
    #pragma unroll
    for (int s8 = 0; s8 < 8; ++s8)
        *(u16x8*)(dst + s8*8) = *(const u16x8*)&Cs[w][l][s8*8];
}

// ---- 2: per-row sums of ek (bf16-consistent) -------------------------------
__global__ __launch_bounds__(256) void ksum_pass(
    const unsigned short* __restrict__ ek, float* __restrict__ ksum)
{
    const int row = blockIdx.x;              // b*256 + c
    const unsigned short* p = ek + (size_t)row * NPIX;
    const int t = threadIdx.x;
    __shared__ float red[256];
    float s = 0.f;
    for (int i = t*8; i < NPIX; i += 2048) {
        u16x8 u = *(const u16x8*)(p + i);
        #pragma unroll
        for (int j = 0; j < 8; ++j) s += bf2f(u[j]);
    }
    red[t] = s; __syncthreads();
    for (int st = 128; st > 0; st >>= 1) {
        if (t < st) red[t] += red[t+st];
        __syncthreads();
    }
    if (t == 0) ksum[row] = red[0];
}

// ---- 3: Tpart[b][chunk] = ek @ x^T via MFMA (128x128 tile, K=2048) ---------
__global__ __launch_bounds__(256) void t_mfma(
    const unsigned short* __restrict__ ek, const float* __restrict__ x,
    float* __restrict__ Tpart)
{
    __shared__ unsigned short As[128][40];
    __shared__ unsigned short Bs[128][40];
    const int quad  = blockIdx.x;        // 0..3 -> (m-tile, c-tile)
    const int chunk = blockIdx.y;        // 0..7
    const int b     = blockIdx.z;
    const int mt = (quad >> 1) * 128;    // key-channel tile
    const int ct = (quad & 1) * 128;     // channel tile
    const int t  = threadIdx.x;
    const int w  = t >> 6, l = t & 63;
    const int lm = l & 15, lg = l >> 4;
    const int mw = (w & 1) * 64, cw = (w >> 1) * 64;
    const int sr = t >> 1, sh = (t & 1) * 16;

    const unsigned short* ekb = ek + ((size_t)b*256 + mt) * NPIX;
    const float*          xb  = x  + ((size_t)b*256 + ct) * NPIX;

    f32x4 acc[4][4] = {};
    const int p0base = chunk * 2048;
    for (int p0 = p0base; p0 < p0base + 2048; p0 += 32) {
        {   // stage A: ek rows (bf16 direct)
            const unsigned short* src = ekb + (size_t)sr * NPIX + p0 + sh;
            *(u16x8*)&As[sr][sh]     = *(const u16x8*)src;
            *(u16x8*)&As[sr][sh + 8] = *(const u16x8*)(src + 8);
        }
        {   // stage B: x rows (fp32 -> bf16)
            const float* src = xb + (size_t)sr * NPIX + p0 + sh;
            u16x8 a, c;
            #pragma unroll
            for (int u = 0; u < 8; ++u) { a[u] = f2bf(src[u]); c[u] = f2bf(src[8+u]); }
            *(u16x8*)&Bs[sr][sh]     = a;
            *(u16x8*)&Bs[sr][sh + 8] = c;
        }
        __syncthreads();
        bf16x8 afr[4], bfr[4];
        #pragma unroll
        for (int i = 0; i < 4; ++i) afr[i] = *(const bf16x8*)&As[mw + i*16 + lm][lg*8];
        #pragma unroll
        for (int j = 0; j < 4; ++j) bfr[j] = *(const bf16x8*)&Bs[cw + j*16 + lm][lg*8];
        #pragma unroll
        for (int i = 0; i < 4; ++i)
            #pragma unroll
            for (int j = 0; j < 4; ++j)
                acc[i][j] = __builtin_amdgcn_mfma_f32_16x16x32_bf16(afr[i], bfr[j], acc[i][j], 0, 0, 0);
        __syncthreads();
    }

    float* dst = Tpart + (((size_t)b*8 + chunk) * 256) * 256;
    #pragma unroll
    for (int i = 0; i < 4; ++i)
        #pragma unroll
        for (int r = 0; r < 4; ++r) {
            const int gm = mt + mw + i*16 + lg*4 + r;
            #pragma unroll
            for (int j = 0; j < 4; ++j)
                dst[(size_t)gm * 256 + ct + cw + j*16 + lm] = acc[i][j][r];
        }
}

// ---- 4a: reduce Tpart chunks in place (chunk 0 slot), fold 1/ksum ----------
__global__ __launch_bounds__(256) void treduce(
    float* __restrict__ Tpart, const float* __restrict__ ksum)
{
    const int gid = blockIdx.x * 256 + threadIdx.x;   // 0..131071 (x4 floats)
    const int b   = gid >> 14;
    const int rem = gid & 16383;
    const int r   = rem >> 6;
    const int c4  = (rem & 63) * 4;
    float* base = Tpart + (((size_t)b*8) * 256 + r) * 256 + c4;   // chunk 0
    f32x4 s = *(f32x4*)base;
    #pragma unroll
    for (int ch = 1; ch < 8; ++ch) {
        f32x4 v = *(const f32x4*)(base + (size_t)ch * 65536);
        s.x += v.x; s.y += v.y; s.z += v.z; s.w += v.w;
    }
    const float inv = 1.0f / ksum[b*256 + r];
    s.x *= inv; s.y *= inv; s.z *= inv; s.w *= inv;
    *(f32x4*)base = s;   // each thread owns its address: race-free
}

// ---- 4b: ctx[b][h][d][e] = Tred[b][h*32+d,:]·Wv[h*64+e,:] + bv[h*64+e] ----
__global__ __launch_bounds__(256) void ctx_pass(
    const float* __restrict__ Tpart, const float* __restrict__ Wv,
    const float* __restrict__ bv, float* __restrict__ ctx)
{
    const int gid = blockIdx.x * 256 + threadIdx.x;   // 0..131071
    const int b   = gid >> 14;
    const int rem = gid & 16383;
    const int h   = rem >> 11;
    const int de  = rem & 2047;
    const int d   = de >> 6;
    const int e   = de & 63;
    const float* tp = Tpart + (((size_t)b*8) * 256 + h*32 + d) * 256;  // Tred row
    const float* wv = Wv + (size_t)(h*64 + e) * 256;
    float sx = 0.f, sy = 0.f, sz = 0.f, sw = 0.f;
    #pragma unroll 8
    for (int c = 0; c < 256; c += 4) {
        f32x4 a = *(const f32x4*)(tp + c);
        f32x4 w = *(const f32x4*)(wv + c);
        sx = fmaf(a.x, w.x, sx); sy = fmaf(a.y, w.y, sy);
        sz = fmaf(a.z, w.z, sz); sw = fmaf(a.w, w.w, sw);
    }
    ctx[gid] = (sx + sy) + (sz + sw) + bv[h*64 + e];
}

// ---- 4c: M[b][o][h*32+d] = sum_e Wo[o][h*64+e]*ctx[b][h][d][e] (bf16) ------
__global__ __launch_bounds__(256) void mpass(
    const float* __restrict__ ctx, const float* __restrict__ Wo,
    unsigned short* __restrict__ Mb)
{
    const int gid = blockIdx.x * 256 + threadIdx.x;   // 0..524287
    const int b   = gid >> 16;
    const int rem = gid & 65535;
    const int o   = rem >> 8;
    const int dg  = rem & 255;
    const int h   = dg >> 5;
    const int d   = dg & 31;
    const float* cp = ctx + ((size_t)b*8 + h) * 2048 + d*64;
    const float* wp = Wo + (size_t)o * 512 + h*64;
    float sx = 0.f, sy = 0.f, sz = 0.f, sw = 0.f;
    #pragma unroll
    for (int e = 0; e < 64; e += 4) {
        f32x4 a = *(const f32x4*)(cp + e);
        f32x4 w = *(const f32x4*)(wp + e);
        sx = fmaf(a.x, w.x, sx); sy = fmaf(a.y, w.y, sy);
        sz = fmaf(a.z, w.z, sz); sw = fmaf(a.w, w.w, sw);
    }
    Mb[((size_t)b*256 + o) * 256 + dg] = f2bf((sx + sy) + (sz + sw));
}

// ---- 8: invZ[b][n][h] = 1 / sum_{c in head h} eqT[b][n][c] -----------------
__global__ __launch_bounds__(256) void invz_pass(
    const unsigned short* __restrict__ eqT, float* __restrict__ invZ)
{
    const int b = blockIdx.y;
    const int n = blockIdx.x * 256 + threadIdx.x;
    const unsigned short* row = eqT + ((size_t)b * NPIX + n) * 256;
    float* o = invZ + ((size_t)b * NPIX + n) * 8;
    #pragma unroll
    for (int h = 0; h < 8; ++h) {
        float s = 0.f;
        #pragma unroll
        for (int u = 0; u < 4; ++u) {
            u16x8 v = *(const u16x8*)(row + h*32 + u*8);
            #pragma unroll
            for (int e = 0; e < 8; ++e) s += bf2f(v[e]);
        }
        o[h] = 1.0f / s;
    }
}

// ---- 9: out = M[b] @ (eqT^T * invZ) + bo via MFMA --------------------------
__global__ __launch_bounds__(256) void out_mfma(
    const unsigned short* __restrict__ eqT, const float* __restrict__ invZ,
    const unsigned short* __restrict__ Mb, const float* __restrict__ bo,
    float* __restrict__ out)
{
    __shared__ unsigned short As[128][40];
    __shared__ unsigned short Bs[128][40];
    const int b  = blockIdx.z;
    const int m0 = blockIdx.y * 128;
    const int n0 = blockIdx.x * 128;
    const int t  = threadIdx.x;
    const int w  = t >> 6, l = t & 63;
    const int lm = l & 15, lg = l >> 4;
    const int mw = (w & 1) * 64, nw = (w >> 1) * 64;
    const int sr = t >> 1, sh = (t & 1) * 16;

    const unsigned short* Ab  = Mb  + ((size_t)b*256 + m0) * 256;
    const unsigned short* Bb  = eqT + (size_t)b * NPIX * 256;
    const float*          izb = invZ + (size_t)b * NPIX * 8;

    f32x4 acc[4][4] = {};
    for (int k0 = 0; k0 < 256; k0 += 32) {
        {   // stage A: Mb rows
            const unsigned short* src = Ab + (size_t)sr * 256 + k0 + sh;
            *(u16x8*)&As[sr][sh]     = *(const u16x8*)src;
            *(u16x8*)&As[sr][sh + 8] = *(const u16x8*)(src + 8);
        }
        {   // stage B: eqT rows * invZ (head = k0>>5, one head per K-step)
            const unsigned short* src = Bb + (size_t)(n0 + sr) * 256 + k0 + sh;
            const float iz = izb[(size_t)(n0 + sr) * 8 + (k0 >> 5)];
            u16x8 a = *(const u16x8*)src, c = *(const u16x8*)(src + 8);
            u16x8 oa, oc;
            #pragma unroll
            for (int u = 0; u < 8; ++u) {
                oa[u] = f2bf(bf2f(a[u]) * iz);
                oc[u] = f2bf(bf2f(c[u]) * iz);
            }
            *(u16x8*)&Bs[sr][sh]     = oa;
            *(u16x8*)&Bs[sr][sh + 8] = oc;
        }
        __syncthreads();
        bf16x8 afr[4], bfr[4];
        #pragma unroll
        for (int i = 0; i < 4; ++i) afr[i] = *(const bf16x8*)&As[mw + i*16 + lm][lg*8];
        #pragma unroll
        for (int j = 0; j < 4; ++j) bfr[j] = *(const bf16x8*)&Bs[nw + j*16 + lm][lg*8];
        #pragma unroll
        for (int i = 0; i < 4; ++i)
            #pragma unroll
            for (int j = 0; j < 4; ++j)
                acc[i][j] = __builtin_amdgcn_mfma_f32_16x16x32_bf16(afr[i], bfr[j], acc[i][j], 0, 0, 0);
        __syncthreads();
    }

    #pragma unroll
    for (int i = 0; i < 4; ++i) {
        const f32x4 bb4 = *(const f32x4*)(bo + m0 + mw + i*16 + lg*4);
        #pragma unroll
        for (int r = 0; r < 4; ++r) {
            const int gm = m0 + mw + i*16 + lg*4 + r;
            float* dst = out + ((size_t)b*256 + gm) * NPIX + n0 + nw;
            #pragma unroll
            for (int j = 0; j < 4; ++j)
                dst[j*16 + lm] = acc[i][j][r] + bb4[r];
        }
    }
}

// ---------------------------------------------------------------------------
extern "C" void kernel_launch(void* const* d_in, const int* in_sizes, int n_in,
                              void* d_out, int out_size, void* d_ws, size_t ws_size,
                              hipStream_t stream)
{
    const float* x  = (const float*)d_in[0];
    const float* Wq = (const float*)d_in[1];
    const float* bq = (const float*)d_in[2];
    const float* Wk = (const float*)d_in[3];
    const float* bk = (const float*)d_in[4];
    const float* Wv = (const float*)d_in[5];
    const float* bv = (const float*)d_in[6];
    const float* Wo = (const float*)d_in[7];
    const float* bo = (const float*)d_in[8];
    float* out = (float*)d_out;

    // workspace (89,399,296 B total; ek and eqT share the first region —
    // ek is dead after t_mfma, eqT written afterwards; ctx borrows the invZ
    // region, which is only written by invz_pass later):
    //   [0,          67108864)  ek / eqT  bf16
    //   [67108864,   83886080)  Tpart f32 [8][8][256][256] (chunk0 -> Tred in place)
    //   [83886080,   88080384)  invZ  f32 [8][16384][8]    (ctx f32 [8][8][32][64] early)
    //   [88080384,   88088576)  ksum  f32 [2048]
    //   [88088576,   89137152)  Mb    bf16 [8][256][256]
    //   [89137152,   89268224)  Wqb   bf16
    //   [89268224,   89399296)  Wkb   bf16
    if (ws_size < (size_t)89399296) return;  // fail loud, not crash
    char* wsb = (char*)d_ws;
    unsigned short* ekq  = (unsigned short*)wsb;
    float*          Tpart= (float*)(wsb + 67108864);
    float*          invZ = (float*)(wsb + 83886080);
    float*          ksum = (float*)(wsb + 88080384);
    unsigned short* Mb   = (unsigned short*)(wsb + 88088576);
    unsigned short* Wqb  = (unsigned short*)(wsb + 89137152);
    unsigned short* Wkb  = (unsigned short*)(wsb + 89268224);
    float*          ctx  = invZ;   // borrowed until invz_pass

    prep             <<<256,              256, 0, stream>>>(Wq, Wk, Wqb, Wkb);
    proj_mfma<false> <<<dim3(128, 2, 8),  256, 0, stream>>>(x, Wkb, bk, ekq);
    ksum_pass        <<<2048,             256, 0, stream>>>(ekq, ksum);
    t_mfma           <<<dim3(4, 8, 8),    256, 0, stream>>>(ekq, x, Tpart);
    treduce          <<<512,              256, 0, stream>>>(Tpart, ksum);
    ctx_pass         <<<512,              256, 0, stream>>>(Tpart, Wv, bv, ctx);
    mpass            <<<2048,             256, 0, stream>>>(ctx, Wo, Mb);
    proj_mfma<true>  <<<dim3(128, 2, 8),  256, 0, stream>>>(x, Wqb, bq, ekq);
    invz_pass        <<<dim3(64, 8),      256, 0, stream>>>(ekq, invZ);
    out_mfma         <<<dim3(128, 2, 8),  256, 0, stream>>>(ekq, invZ, Mb, bo, out);
}

// Round 5
// 309.296 us; speedup vs baseline: 3.5062x; 1.0879x over previous
//
#include <hip/hip_runtime.h>
#include <hip/hip_bf16.h>
#include <cstddef>

// ILA_10986526343542: linear attention block, bf16-MFMA pipeline.
// x:[8,256,128,128] fp32. Math:
//   ek  = exp(s*(Wk@x+bk)) bf16 [b][c][n]      (proj_mfma<false>)
//   ksum[b,c] = sum_n ek                        (ksum_pass)
//   T   = ek @ x^T  (split over 8 n-chunks)     (t_mfma -> Tpart)
//   Tred= (sum_chunks T)/ksum  (in-place ch.0)  (treduce)
//   ctx = Tred@Wv^T + bv                        (ctx_pass)
//   M   = Wo_h @ ctx_h^T  (bf16)                (mpass)
//   eqT = exp(s*(Wq@x+bq)) bf16 [b][n][c]      (proj_mfma<true>)
//   invZ[b,n,h] = 1/sum_{c in head} eqT[n][c]   (invz_pass)
//   out = M @ (eqT^T * invZ) + bo               (out_mfma)

constexpr int   NPIX     = 16384;
constexpr float QK_SCALE = 0.42044820762685725f;  // 32^-0.25

typedef __attribute__((ext_vector_type(8))) short          bf16x8;
typedef __attribute__((ext_vector_type(8))) unsigned short u16x8;
typedef __attribute__((ext_vector_type(4))) float          f32x4;

__device__ __forceinline__ float bf2f(unsigned short v) {
    union { unsigned int u; float f; } c; c.u = ((unsigned int)v) << 16; return c.f;
}
__device__ __forceinline__ unsigned short f2bf(float f) {
    union { __hip_bfloat16 h; unsigned short s; } c; c.h = __float2bfloat16(f); return c.s;
}

// ---- 0: weights to bf16 ----------------------------------------------------
__global__ __launch_bounds__(256) void prep(
    const float* __restrict__ Wq, const float* __restrict__ Wk,
    unsigned short* __restrict__ Wqb, unsigned short* __restrict__ Wkb)
{
    const int i = blockIdx.x * 256 + threadIdx.x;   // 65536 total
    Wqb[i] = f2bf(Wq[i]);
    Wkb[i] = f2bf(Wk[i]);
}

// ---- 1/7: projection via MFMA, LDS-staged + transposed B -------------------
// QPASS=false: eout = ek  [b][c][n] row-major
// QPASS=true : eout = eqT [b][n][c] row-major (transposed store)
// LDS phases (aliased, 36864 B):
//   K-loop : As[128][40] shorts (10240 B) | BsT[128][40] shorts (10240 B)
//   epilog : Cs[4][64][72] shorts (36864 B)
template<bool QPASS>
__global__ __launch_bounds__(256) void proj_mfma(
    const float* __restrict__ x, const unsigned short* __restrict__ Wb,
    const float* __restrict__ bias, unsigned short* __restrict__ eout)
{
    __shared__ alignas(16) unsigned char smem[36864];
    unsigned short (*As)[40]      = (unsigned short(*)[40])smem;
    unsigned short (*BsT)[40]     = (unsigned short(*)[40])(smem + 10240);
    unsigned short (*Cs)[64][72]  = (unsigned short(*)[64][72])smem;

    const int b  = blockIdx.z;
    const int m0 = blockIdx.y * 128;
    const int n0 = blockIdx.x * 128;
    const int t  = threadIdx.x;
    const int w  = t >> 6, l = t & 63;
    const int lm = l & 15, lg = l >> 4;
    const int mwl = (w & 1) * 64;          // wave m offset within tile
    const int nwl = (w >> 1) * 64;         // wave n offset within tile

    const float* xb = x + (size_t)b * 256 * NPIX + n0;

    // stage mappings
    const int asr = t >> 1, ash = (t & 1) * 16;        // A: row 0..127, k-half
    const int np  = (t & 63) * 2, kq = (t >> 6) * 8;   // B: n-pair, k-group

    f32x4 acc[4][4] = {};
    for (int k0 = 0; k0 < 256; k0 += 32) {
        {   // stage A: W rows (bf16, k-contiguous)
            const unsigned short* src = Wb + (size_t)(m0 + asr) * 256 + k0 + ash;
            *(u16x8*)&As[asr][ash]     = *(const u16x8*)src;
            *(u16x8*)&As[asr][ash + 8] = *(const u16x8*)(src + 8);
        }
        {   // stage B: x columns -> transposed LDS tile BsT[n][k]
            const float* src = xb + (size_t)(k0 + kq) * NPIX + np;
            float2 v[8];
            #pragma unroll
            for (int r = 0; r < 8; ++r)
                v[r] = *(const float2*)(src + (size_t)r * NPIX);
            u16x8 pa, pb;
            #pragma unroll
            for (int r = 0; r < 8; ++r) { pa[r] = f2bf(v[r].x); pb[r] = f2bf(v[r].y); }
            *(u16x8*)&BsT[np][kq]     = pa;
            *(u16x8*)&BsT[np + 1][kq] = pb;
        }
        __syncthreads();
        bf16x8 afr[4], bfr[4];
        #pragma unroll
        for (int i = 0; i < 4; ++i) afr[i] = *(const bf16x8*)&As[mwl + i*16 + lm][lg*8];
        #pragma unroll
        for (int j = 0; j < 4; ++j) bfr[j] = *(const bf16x8*)&BsT[nwl + j*16 + lm][lg*8];
        #pragma unroll
        for (int i = 0; i < 4; ++i)
            #pragma unroll
            for (int j = 0; j < 4; ++j)
                acc[i][j] = __builtin_amdgcn_mfma_f32_16x16x32_bf16(afr[i], bfr[j], acc[i][j], 0, 0, 0);
        __syncthreads();
    }

    // epilogue: exp + bf16, bounce through LDS for coalesced stores
    const int mw = m0 + mwl, nw = n0 + nwl;
    #pragma unroll
    for (int i = 0; i < 4; ++i) {
        const f32x4 bb4 = *(const f32x4*)(bias + mw + i*16 + lg*4);
        #pragma unroll
        for (int r = 0; r < 4; ++r) {
            const int row = i*16 + lg*4 + r;
            #pragma unroll
            for (int j = 0; j < 4; ++j) {
                const int col = j*16 + lm;
                const unsigned short bs = f2bf(__expf(QK_SCALE * (acc[i][j][r] + bb4[r])));
                if (QPASS) Cs[w][col][row] = bs;   // [n-local][c-local]
                else       Cs[w][row][col] = bs;   // [c-local][n-local]
            }
        }
    }
    __syncthreads();

    unsigned short* dst;
    if (QPASS) dst = eout + ((size_t)b * NPIX + nw + l) * 256 + mw;   // eqT row
    else       dst = eout + ((size_t)b * 256 + mw + l) * NPIX + nw;   // ek row
    #pragma unroll
    for (int s8 = 0; s8 < 8; ++s8)
        *(u16x8*)(dst + s8*8) = *(const u16x8*)&Cs[w][l][s8*8];
}

// ---- 2: per-row sums of ek (bf16-consistent) -------------------------------
__global__ __launch_bounds__(256) void ksum_pass(
    const unsigned short* __restrict__ ek, float* __restrict__ ksum)
{
    const int row = blockIdx.x;              // b*256 + c
    const unsigned short* p = ek + (size_t)row * NPIX;
    const int t = threadIdx.x;
    __shared__ float red[256];
    float s = 0.f;
    for (int i = t*8; i < NPIX; i += 2048) {
        u16x8 u = *(const u16x8*)(p + i);
        #pragma unroll
        for (int j = 0; j < 8; ++j) s += bf2f(u[j]);
    }
    red[t] = s; __syncthreads();
    for (int st = 128; st > 0; st >>= 1) {
        if (t < st) red[t] += red[t+st];
        __syncthreads();
    }
    if (t == 0) ksum[row] = red[0];
}

// ---- 3: Tpart[b][chunk] = ek @ x^T via MFMA (128x128 tile, K=2048) ---------
__global__ __launch_bounds__(256) void t_mfma(
    const unsigned short* __restrict__ ek, const float* __restrict__ x,
    float* __restrict__ Tpart)
{
    __shared__ unsigned short As[128][40];
    __shared__ unsigned short Bs[128][40];
    const int quad  = blockIdx.x;        // 0..3 -> (m-tile, c-tile)
    const int chunk = blockIdx.y;        // 0..7
    const int b     = blockIdx.z;
    const int mt = (quad >> 1) * 128;    // key-channel tile
    const int ct = (quad & 1) * 128;     // channel tile
    const int t  = threadIdx.x;
    const int w  = t >> 6, l = t & 63;
    const int lm = l & 15, lg = l >> 4;
    const int mw = (w & 1) * 64, cw = (w >> 1) * 64;
    const int sr = t >> 1, sh = (t & 1) * 16;

    const unsigned short* ekb = ek + ((size_t)b*256 + mt) * NPIX;
    const float*          xb  = x  + ((size_t)b*256 + ct) * NPIX;

    f32x4 acc[4][4] = {};
    const int p0base = chunk * 2048;
    for (int p0 = p0base; p0 < p0base + 2048; p0 += 32) {
        {   // stage A: ek rows (bf16 direct)
            const unsigned short* src = ekb + (size_t)sr * NPIX + p0 + sh;
            *(u16x8*)&As[sr][sh]     = *(const u16x8*)src;
            *(u16x8*)&As[sr][sh + 8] = *(const u16x8*)(src + 8);
        }
        {   // stage B: x rows (fp32 -> bf16)
            const float* src = xb + (size_t)sr * NPIX + p0 + sh;
            u16x8 a, c;
            #pragma unroll
            for (int u = 0; u < 8; ++u) { a[u] = f2bf(src[u]); c[u] = f2bf(src[8+u]); }
            *(u16x8*)&Bs[sr][sh]     = a;
            *(u16x8*)&Bs[sr][sh + 8] = c;
        }
        __syncthreads();
        bf16x8 afr[4], bfr[4];
        #pragma unroll
        for (int i = 0; i < 4; ++i) afr[i] = *(const bf16x8*)&As[mw + i*16 + lm][lg*8];
        #pragma unroll
        for (int j = 0; j < 4; ++j) bfr[j] = *(const bf16x8*)&Bs[cw + j*16 + lm][lg*8];
        #pragma unroll
        for (int i = 0; i < 4; ++i)
            #pragma unroll
            for (int j = 0; j < 4; ++j)
                acc[i][j] = __builtin_amdgcn_mfma_f32_16x16x32_bf16(afr[i], bfr[j], acc[i][j], 0, 0, 0);
        __syncthreads();
    }

    float* dst = Tpart + (((size_t)b*8 + chunk) * 256) * 256;
    #pragma unroll
    for (int i = 0; i < 4; ++i)
        #pragma unroll
        for (int r = 0; r < 4; ++r) {
            const int gm = mt + mw + i*16 + lg*4 + r;
            #pragma unroll
            for (int j = 0; j < 4; ++j)
                dst[(size_t)gm * 256 + ct + cw + j*16 + lm] = acc[i][j][r];
        }
}

// ---- 4a: reduce Tpart chunks in place (chunk 0 slot), fold 1/ksum ----------
__global__ __launch_bounds__(256) void treduce(
    float* __restrict__ Tpart, const float* __restrict__ ksum)
{
    const int gid = blockIdx.x * 256 + threadIdx.x;   // 0..131071 (x4 floats)
    const int b   = gid >> 14;
    const int rem = gid & 16383;
    const int r   = rem >> 6;
    const int c4  = (rem & 63) * 4;
    float* base = Tpart + (((size_t)b*8) * 256 + r) * 256 + c4;   // chunk 0
    f32x4 s = *(f32x4*)base;
    #pragma unroll
    for (int ch = 1; ch < 8; ++ch) {
        f32x4 v = *(const f32x4*)(base + (size_t)ch * 65536);
        s.x += v.x; s.y += v.y; s.z += v.z; s.w += v.w;
    }
    const float inv = 1.0f / ksum[b*256 + r];
    s.x *= inv; s.y *= inv; s.z *= inv; s.w *= inv;
    *(f32x4*)base = s;   // each thread owns its address: race-free
}

// ---- 4b: ctx[b][h][d][e] = Tred[b][h*32+d,:]·Wv[h*64+e,:] + bv[h*64+e] ----
__global__ __launch_bounds__(256) void ctx_pass(
    const float* __restrict__ Tpart, const float* __restrict__ Wv,
    const float* __restrict__ bv, float* __restrict__ ctx)
{
    const int gid = blockIdx.x * 256 + threadIdx.x;   // 0..131071
    const int b   = gid >> 14;
    const int rem = gid & 16383;
    const int h   = rem >> 11;
    const int de  = rem & 2047;
    const int d   = de >> 6;
    const int e   = de & 63;
    const float* tp = Tpart + (((size_t)b*8) * 256 + h*32 + d) * 256;  // Tred row
    const float* wv = Wv + (size_t)(h*64 + e) * 256;
    float sx = 0.f, sy = 0.f, sz = 0.f, sw = 0.f;
    #pragma unroll 8
    for (int c = 0; c < 256; c += 4) {
        f32x4 a = *(const f32x4*)(tp + c);
        f32x4 w = *(const f32x4*)(wv + c);
        sx = fmaf(a.x, w.x, sx); sy = fmaf(a.y, w.y, sy);
        sz = fmaf(a.z, w.z, sz); sw = fmaf(a.w, w.w, sw);
    }
    ctx[gid] = (sx + sy) + (sz + sw) + bv[h*64 + e];
}

// ---- 4c: M[b][o][h*32+d] = sum_e Wo[o][h*64+e]*ctx[b][h][d][e] (bf16) ------
__global__ __launch_bounds__(256) void mpass(
    const float* __restrict__ ctx, const float* __restrict__ Wo,
    unsigned short* __restrict__ Mb)
{
    const int gid = blockIdx.x * 256 + threadIdx.x;   // 0..524287
    const int b   = gid >> 16;
    const int rem = gid & 65535;
    const int o   = rem >> 8;
    const int dg  = rem & 255;
    const int h   = dg >> 5;
    const int d   = dg & 31;
    const float* cp = ctx + ((size_t)b*8 + h) * 2048 + d*64;
    const float* wp = Wo + (size_t)o * 512 + h*64;
    float sx = 0.f, sy = 0.f, sz = 0.f, sw = 0.f;
    #pragma unroll
    for (int e = 0; e < 64; e += 4) {
        f32x4 a = *(const f32x4*)(cp + e);
        f32x4 w = *(const f32x4*)(wp + e);
        sx = fmaf(a.x, w.x, sx); sy = fmaf(a.y, w.y, sy);
        sz = fmaf(a.z, w.z, sz); sw = fmaf(a.w, w.w, sw);
    }
    Mb[((size_t)b*256 + o) * 256 + dg] = f2bf((sx + sy) + (sz + sw));
}

// ---- 8: invZ[b][n][h] = 1 / sum_{c in head h} eqT[b][n][c] -----------------
__global__ __launch_bounds__(256) void invz_pass(
    const unsigned short* __restrict__ eqT, float* __restrict__ invZ)
{
    const int b = blockIdx.y;
    const int n = blockIdx.x * 256 + threadIdx.x;
    const unsigned short* row = eqT + ((size_t)b * NPIX + n) * 256;
    float* o = invZ + ((size_t)b * NPIX + n) * 8;
    #pragma unroll
    for (int h = 0; h < 8; ++h) {
        float s = 0.f;
        #pragma unroll
        for (int u = 0; u < 4; ++u) {
            u16x8 v = *(const u16x8*)(row + h*32 + u*8);
            #pragma unroll
            for (int e = 0; e < 8; ++e) s += bf2f(v[e]);
        }
        o[h] = 1.0f / s;
    }
}

// ---- 9: out = M[b] @ (eqT^T * invZ) + bo via MFMA --------------------------
__global__ __launch_bounds__(256) void out_mfma(
    const unsigned short* __restrict__ eqT, const float* __restrict__ invZ,
    const unsigned short* __restrict__ Mb, const float* __restrict__ bo,
    float* __restrict__ out)
{
    __shared__ unsigned short As[128][40];
    __shared__ unsigned short Bs[128][40];
    const int b  = blockIdx.z;
    const int m0 = blockIdx.y * 128;
    const int n0 = blockIdx.x * 128;
    const int t  = threadIdx.x;
    const int w  = t >> 6, l = t & 63;
    const int lm = l & 15, lg = l >> 4;
    const int mw = (w & 1) * 64, nw = (w >> 1) * 64;
    const int sr = t >> 1, sh = (t & 1) * 16;

    const unsigned short* Ab  = Mb  + ((size_t)b*256 + m0) * 256;
    const unsigned short* Bb  = eqT + (size_t)b * NPIX * 256;
    const float*          izb = invZ + (size_t)b * NPIX * 8;

    f32x4 acc[4][4] = {};
    for (int k0 = 0; k0 < 256; k0 += 32) {
        {   // stage A: Mb rows
            const unsigned short* src = Ab + (size_t)sr * 256 + k0 + sh;
            *(u16x8*)&As[sr][sh]     = *(const u16x8*)src;
            *(u16x8*)&As[sr][sh + 8] = *(const u16x8*)(src + 8);
        }
        {   // stage B: eqT rows * invZ (head = k0>>5, one head per K-step)
            const unsigned short* src = Bb + (size_t)(n0 + sr) * 256 + k0 + sh;
            const float iz = izb[(size_t)(n0 + sr) * 8 + (k0 >> 5)];
            u16x8 a = *(const u16x8*)src, c = *(const u16x8*)(src + 8);
            u16x8 oa, oc;
            #pragma unroll
            for (int u = 0; u < 8; ++u) {
                oa[u] = f2bf(bf2f(a[u]) * iz);
                oc[u] = f2bf(bf2f(c[u]) * iz);
            }
            *(u16x8*)&Bs[sr][sh]     = oa;
            *(u16x8*)&Bs[sr][sh + 8] = oc;
        }
        __syncthreads();
        bf16x8 afr[4], bfr[4];
        #pragma unroll
        for (int i = 0; i < 4; ++i) afr[i] = *(const bf16x8*)&As[mw + i*16 + lm][lg*8];
        #pragma unroll
        for (int j = 0; j < 4; ++j) bfr[j] = *(const bf16x8*)&Bs[nw + j*16 + lm][lg*8];
        #pragma unroll
        for (int i = 0; i < 4; ++i)
            #pragma unroll
            for (int j = 0; j < 4; ++j)
                acc[i][j] = __builtin_amdgcn_mfma_f32_16x16x32_bf16(afr[i], bfr[j], acc[i][j], 0, 0, 0);
        __syncthreads();
    }

    #pragma unroll
    for (int i = 0; i < 4; ++i) {
        const f32x4 bb4 = *(const f32x4*)(bo + m0 + mw + i*16 + lg*4);
        #pragma unroll
        for (int r = 0; r < 4; ++r) {
            const int gm = m0 + mw + i*16 + lg*4 + r;
            float* dst = out + ((size_t)b*256 + gm) * NPIX + n0 + nw;
            #pragma unroll
            for (int j = 0; j < 4; ++j)
                dst[j*16 + lm] = acc[i][j][r] + bb4[r];
        }
    }
}

// ---------------------------------------------------------------------------
extern "C" void kernel_launch(void* const* d_in, const int* in_sizes, int n_in,
                              void* d_out, int out_size, void* d_ws, size_t ws_size,
                              hipStream_t stream)
{
    const float* x  = (const float*)d_in[0];
    const float* Wq = (const float*)d_in[1];
    const float* bq = (const float*)d_in[2];
    const float* Wk = (const float*)d_in[3];
    const float* bk = (const float*)d_in[4];
    const float* Wv = (const float*)d_in[5];
    const float* bv = (const float*)d_in[6];
    const float* Wo = (const float*)d_in[7];
    const float* bo = (const float*)d_in[8];
    float* out = (float*)d_out;

    // workspace (89,399,296 B total; ek and eqT share the first region —
    // ek is dead after t_mfma, eqT written afterwards; ctx borrows the invZ
    // region, which is only written by invz_pass later):
    //   [0,          67108864)  ek / eqT  bf16
    //   [67108864,   83886080)  Tpart f32 [8][8][256][256] (chunk0 -> Tred in place)
    //   [83886080,   88080384)  invZ  f32 [8][16384][8]    (ctx f32 [8][8][32][64] early)
    //   [88080384,   88088576)  ksum  f32 [2048]
    //   [88088576,   89137152)  Mb    bf16 [8][256][256]
    //   [89137152,   89268224)  Wqb   bf16
    //   [89268224,   89399296)  Wkb   bf16
    if (ws_size < (size_t)89399296) return;  // fail loud, not crash
    char* wsb = (char*)d_ws;
    unsigned short* ekq  = (unsigned short*)wsb;
    float*          Tpart= (float*)(wsb + 67108864);
    float*          invZ = (float*)(wsb + 83886080);
    float*          ksum = (float*)(wsb + 88080384);
    unsigned short* Mb   = (unsigned short*)(wsb + 88088576);
    unsigned short* Wqb  = (unsigned short*)(wsb + 89137152);
    unsigned short* Wkb  = (unsigned short*)(wsb + 89268224);
    float*          ctx  = invZ;   // borrowed until invz_pass

    prep             <<<256,              256, 0, stream>>>(Wq, Wk, Wqb, Wkb);
    proj_mfma<false> <<<dim3(128, 2, 8),  256, 0, stream>>>(x, Wkb, bk, ekq);
    ksum_pass        <<<2048,             256, 0, stream>>>(ekq, ksum);
    t_mfma           <<<dim3(4, 8, 8),    256, 0, stream>>>(ekq, x, Tpart);
    treduce          <<<512,              256, 0, stream>>>(Tpart, ksum);
    ctx_pass         <<<512,              256, 0, stream>>>(Tpart, Wv, bv, ctx);
    mpass            <<<2048,             256, 0, stream>>>(ctx, Wo, Mb);
    proj_mfma<true>  <<<dim3(128, 2, 8),  256, 0, stream>>>(x, Wqb, bq, ekq);
    invz_pass        <<<dim3(64, 8),      256, 0, stream>>>(ekq, invZ);
    out_mfma         <<<dim3(128, 2, 8),  256, 0, stream>>>(ekq, invZ, Mb, bo, out);
}